// Round 3
// baseline (635.645 us; speedup 1.0000x reference)
//
#include <hip/hip_runtime.h>

// BondAwareEGNN fused layer — round 8.
//
// Round-7 post-mortem: spills gone (hbm back to 3.0e8) but occupancy stuck
// at 43% — VGPR_Count=64 excludes AGPRs; true alloc ~96-128 regs -> 4
// waves/SIMD reg-capped. r6 proved <=64 total spills. More waves is a dead
// end; MfmaUtil 9.8% x 263us = 26us = exact MFMA floor; ~64% of cycles are
// B-fragment latency stalls (128 W-loads : 128 MFMAs = 1:1 per wave).
//
// Round-8: M=32 rows/wave — two accumulator sets share every B load
// (1:2 load:MFMA), blocks halve to 3750. acc 64 AGPR + ~60 VGPR fits the
// (256,4)=128 cap. LDS [128][128] tile = 37.4KB -> still 4 blocks/CU
// (LDS-capped == reg-capped). Barrier-free wave-private rows preserved.
// Node kernel unchanged (isolate one variable).

#define H      128
#define NA     20000
#define NB     60000
#define NBATCH 8

typedef __bf16 bf16;
typedef __bf16 bf16x4 __attribute__((ext_vector_type(4)));
typedef __bf16 bf16x8 __attribute__((ext_vector_type(8)));
typedef float  f32x4  __attribute__((ext_vector_type(4)));

__device__ __forceinline__ float silu_f(float v) {
  float e = __expf(-v);
  return v * __builtin_amdgcn_rcpf(1.0f + e);  // 1-ulp rcp; inf -> 0 ok
}

// XOR-swizzled index into a [R][128] bf16 tile. Row stride 256B (bank
// neutral); 16B chunk index XOR'd with row&7 rotates banks. Bijective per
// row; 8-element chunks stay contiguous so bf16x8 loads/stores still work.
__device__ __forceinline__ int tswz(int row, int col) {
  return (row << 7) + (((((col) >> 3) ^ (row & 7)) << 3) | (col & 7));
}

__global__ void cast_h(const float* __restrict__ src, bf16* __restrict__ dst) {
  int i = blockIdx.x * 256 + threadIdx.x;  // one float4 per thread
  float4 v = *(const float4*)(src + (size_t)i * 4);
  bf16x4 t = {(bf16)v.x, (bf16)v.y, (bf16)v.z, (bf16)v.w};
  *(bf16x4*)(dst + (size_t)i * 4) = t;
}

// fp32 KxN(128) row-major -> bf16 fragment-linear (8 bf16 per lane-frag).
__global__ void pack_w(const float* __restrict__ src, bf16* __restrict__ dst,
                       int K) {
  int i = blockIdx.x * 256 + threadIdx.x;
  if (i >= K * 128) return;
  int k = i >> 7, n = i & 127;
  int nt = n >> 4, ks = k >> 5;
  int lane = (((k >> 3) & 3) << 4) | (n & 15);
  int j = k & 7;
  int KS = K >> 5;
  dst[((((nt * KS + ks) * 64) + lane) << 3) + j] = (bf16)src[i];
}

// ---------------- CSR build ----------------
__global__ void count_deg(const int* __restrict__ bonds,
                          int* __restrict__ degI) {
  int e = blockIdx.x * 256 + threadIdx.x;
  if (e >= NB) return;
  atomicAdd(&degI[bonds[2 * e]], 1);
  atomicAdd(&degI[bonds[2 * e + 1]], 1);
}

// single block, 1024 threads, wave-shfl scan (4 barriers per 1024-chunk)
__global__ void scan_offsets(const int* __restrict__ deg,
                             int* __restrict__ offsets) {
  __shared__ int wsum[16];
  __shared__ int carry;
  const int tid = threadIdx.x;
  const int wave = tid >> 6, lane = tid & 63;
  if (tid == 0) carry = 0;
  __syncthreads();
  for (int base = 0; base < NA; base += 1024) {
    int i = base + tid;
    int v = (i < NA) ? deg[i] : 0;
    int s = v;  // inclusive scan within wave
#pragma unroll
    for (int o = 1; o < 64; o <<= 1) {
      int t = __shfl_up(s, o);
      if (lane >= o) s += t;
    }
    if (lane == 63) wsum[wave] = s;
    __syncthreads();
    if (wave == 0) {  // scan the 16 wave totals
      int w = (lane < 16) ? wsum[lane] : 0;
#pragma unroll
      for (int o = 1; o < 16; o <<= 1) {
        int t = __shfl_up(w, o);
        if (lane >= o) w += t;
      }
      if (lane < 16) wsum[lane] = w;  // inclusive
    }
    __syncthreads();
    int pre = carry + (wave > 0 ? wsum[wave - 1] : 0);
    if (i < NA) offsets[i] = pre + s - v;  // exclusive
    __syncthreads();
    if (tid == 0) carry += wsum[15];
    __syncthreads();
  }
}

__global__ void build_adj(const int* __restrict__ bonds,
                          const int* __restrict__ offsets,
                          int* __restrict__ cursor, int* __restrict__ adj) {
  int e = blockIdx.x * 256 + threadIdx.x;
  if (e >= NB) return;
  int s = bonds[2 * e], d = bonds[2 * e + 1];
  int p = atomicAdd(&cursor[s], 1);
  adj[offsets[s] + p] = (e << 1);        // src endpoint (coord sign -)
  p = atomicAdd(&cursor[d], 1);
  adj[offsets[d] + p] = (e << 1) | 1;    // dst endpoint (coord sign +)
}

// ---------------- message kernel (M=32 per wave) ----------------
__global__ __launch_bounds__(256, 4) void msg_kernel(
    const bf16* __restrict__ hb, const float* __restrict__ x,
    const int* __restrict__ bonds,
    const bf16* __restrict__ W1p, const float* __restrict__ bm1,
    const bf16* __restrict__ W2p, const float* __restrict__ bm2,
    const float* __restrict__ w1c,   // Wm1 row 256 (dist row), fp32[128]
    const bf16* __restrict__ Wc1p, const float* __restrict__ bc1,
    const float* __restrict__ Wc2,
    bf16* __restrict__ msgOut, float* __restrict__ updv) {
  // Single [128][128] swizzled tile: holds T after layer-1, then messages
  // after layer-2 (safe alias: epilogue writes depend on all reads; rows
  // are wave-private).
  __shared__ __align__(16) bf16 Tbuf[128 * 128];
  __shared__ float cds[128 * 3];
  __shared__ float dists[128];
  __shared__ float bm1s[128], bm2s[128], w1cs[128], bc1s[128], wc2s[128];

  const int tid = threadIdx.x, blk = blockIdx.x;

  if (tid < 128) {
    int Rg = blk * 128 + tid;
    int bond = Rg >> 3, batch = Rg & 7;
    int s = bonds[2 * bond], dn = bonds[2 * bond + 1];
    const float* xs = x + (size_t)(batch * NA + s) * 3;
    const float* xd = x + (size_t)(batch * NA + dn) * 3;
    float c0 = xd[0] - xs[0], c1 = xd[1] - xs[1], c2 = xd[2] - xs[2];
    cds[tid * 3 + 0] = c0; cds[tid * 3 + 1] = c1; cds[tid * 3 + 2] = c2;
    dists[tid] = sqrtf(c0 * c0 + c1 * c1 + c2 * c2);
    bm1s[tid] = bm1[tid]; bm2s[tid] = bm2[tid]; w1cs[tid] = w1c[tid];
    bc1s[tid] = bc1[tid]; wc2s[tid] = Wc2[tid];
  }
  __syncthreads();   // the ONLY barrier

  const int lane = tid & 63;
  const int quad = lane >> 4, l16 = lane & 15;
  const int rowBase = (tid >> 6) * 32;   // 32 rows per wave
  const bf16x8* W1v = (const bf16x8*)W1p;
  const bf16x8* W2v = (const bf16x8*)W2p;
  const bf16x8* Wc1v = (const bf16x8*)Wc1p;

  // per-lane A-row metadata, two row sets (rows rowBase+l16, rowBase+16+l16)
  const int Rg0 = blk * 128 + rowBase + l16;
  const int bn0 = Rg0 >> 3, bat0 = Rg0 & 7;
  const bf16* hs0 = hb + (size_t)(bat0 * NA + bonds[2 * bn0]) * H;
  const bf16* hd0 = hb + (size_t)(bat0 * NA + bonds[2 * bn0 + 1]) * H;
  const int Rg1 = Rg0 + 16;
  const int bn1_ = Rg1 >> 3, bat1 = Rg1 & 7;
  const bf16* hs1 = hb + (size_t)(bat1 * NA + bonds[2 * bn1_]) * H;
  const bf16* hd1 = hb + (size_t)(bat1 * NA + bonds[2 * bn1_ + 1]) * H;

  f32x4 acc0[8], acc1[8];
#pragma unroll
  for (int nt = 0; nt < 8; nt++) {
    acc0[nt] = (f32x4){0.f, 0.f, 0.f, 0.f};
    acc1[nt] = (f32x4){0.f, 0.f, 0.f, 0.f};
  }

  // ---- layer 1: K = 256, A-fragments straight from global, B shared x2 ----
#pragma unroll
  for (int ks = 0; ks < 4; ks++) {
    bf16x8 a0 = *(const bf16x8*)(hs0 + ks * 32 + quad * 8);
    bf16x8 a1 = *(const bf16x8*)(hs1 + ks * 32 + quad * 8);
#pragma unroll
    for (int nt = 0; nt < 8; nt++) {
      bf16x8 b = W1v[(nt * 8 + ks) * 64 + lane];
      acc0[nt] = __builtin_amdgcn_mfma_f32_16x16x32_bf16(a0, b, acc0[nt], 0, 0, 0);
      acc1[nt] = __builtin_amdgcn_mfma_f32_16x16x32_bf16(a1, b, acc1[nt], 0, 0, 0);
    }
  }
#pragma unroll
  for (int ks = 4; ks < 8; ks++) {
    bf16x8 a0 = *(const bf16x8*)(hd0 + (ks - 4) * 32 + quad * 8);
    bf16x8 a1 = *(const bf16x8*)(hd1 + (ks - 4) * 32 + quad * 8);
#pragma unroll
    for (int nt = 0; nt < 8; nt++) {
      bf16x8 b = W1v[(nt * 8 + ks) * 64 + lane];
      acc0[nt] = __builtin_amdgcn_mfma_f32_16x16x32_bf16(a0, b, acc0[nt], 0, 0, 0);
      acc1[nt] = __builtin_amdgcn_mfma_f32_16x16x32_bf16(a1, b, acc1[nt], 0, 0, 0);
    }
  }
  // t1 epilogue -> Tbuf (each wave touches only its own 32 rows: no barrier)
#pragma unroll
  for (int nt = 0; nt < 8; nt++) {
    int col = nt * 16 + l16;
    float bb = bm1s[col], wc = w1cs[col];
#pragma unroll
    for (int reg = 0; reg < 4; reg++) {
      int row0 = rowBase + quad * 4 + reg;
      int row1 = row0 + 16;
      float v0 = acc0[nt][reg] + bb + dists[row0] * wc;
      float v1 = acc1[nt][reg] + bb + dists[row1] * wc;
      Tbuf[tswz(row0, col)] = (bf16)silu_f(v0);
      Tbuf[tswz(row1, col)] = (bf16)silu_f(v1);
    }
  }

  // ---- layer 2: K = 128 -> messages (written back over Tbuf) ----
#pragma unroll
  for (int nt = 0; nt < 8; nt++) {
    acc0[nt] = (f32x4){0.f, 0.f, 0.f, 0.f};
    acc1[nt] = (f32x4){0.f, 0.f, 0.f, 0.f};
  }
#pragma unroll
  for (int ks = 0; ks < 4; ks++) {
    bf16x8 a0 = *(const bf16x8*)&Tbuf[tswz(rowBase + l16, ks * 32 + quad * 8)];
    bf16x8 a1 = *(const bf16x8*)&Tbuf[tswz(rowBase + 16 + l16, ks * 32 + quad * 8)];
#pragma unroll
    for (int nt = 0; nt < 8; nt++) {
      bf16x8 b = W2v[(nt * 4 + ks) * 64 + lane];
      acc0[nt] = __builtin_amdgcn_mfma_f32_16x16x32_bf16(a0, b, acc0[nt], 0, 0, 0);
      acc1[nt] = __builtin_amdgcn_mfma_f32_16x16x32_bf16(a1, b, acc1[nt], 0, 0, 0);
    }
  }
#pragma unroll
  for (int nt = 0; nt < 8; nt++) {
    int col = nt * 16 + l16;
    float bb = bm2s[col];
#pragma unroll
    for (int reg = 0; reg < 4; reg++) {
      int row0 = rowBase + quad * 4 + reg;
      int row1 = row0 + 16;
      Tbuf[tswz(row0, col)] = (bf16)silu_f(acc0[nt][reg] + bb);
      Tbuf[tswz(row1, col)] = (bf16)silu_f(acc1[nt][reg] + bb);
    }
  }

  // ---- coord head: silu(messages @ Wc1 + bc1) @ Wc2 ----
#pragma unroll
  for (int nt = 0; nt < 8; nt++) {
    acc0[nt] = (f32x4){0.f, 0.f, 0.f, 0.f};
    acc1[nt] = (f32x4){0.f, 0.f, 0.f, 0.f};
  }
#pragma unroll
  for (int ks = 0; ks < 4; ks++) {
    bf16x8 a0 = *(const bf16x8*)&Tbuf[tswz(rowBase + l16, ks * 32 + quad * 8)];
    bf16x8 a1 = *(const bf16x8*)&Tbuf[tswz(rowBase + 16 + l16, ks * 32 + quad * 8)];
#pragma unroll
    for (int nt = 0; nt < 8; nt++) {
      bf16x8 b = Wc1v[(nt * 4 + ks) * 64 + lane];
      acc0[nt] = __builtin_amdgcn_mfma_f32_16x16x32_bf16(a0, b, acc0[nt], 0, 0, 0);
      acc1[nt] = __builtin_amdgcn_mfma_f32_16x16x32_bf16(a1, b, acc1[nt], 0, 0, 0);
    }
  }

  // copy this wave's 32 message rows to global (coalesced 16B chunks)
#pragma unroll
  for (int i = 0; i < 8; i++) {
    int idx = i * 64 + lane;
    int row = rowBase + (idx >> 4), cg = idx & 15;
    *(bf16x8*)&msgOut[(size_t)(blk * 128 + row) * H + cg * 8] =
        *(const bf16x8*)&Tbuf[tswz(row, cg * 8)];
  }

  float cwp0[4] = {0.f, 0.f, 0.f, 0.f};
  float cwp1[4] = {0.f, 0.f, 0.f, 0.f};
#pragma unroll
  for (int nt = 0; nt < 8; nt++) {
    int col = nt * 16 + l16;
    float bb = bc1s[col], w2 = wc2s[col];
#pragma unroll
    for (int reg = 0; reg < 4; reg++) {
      cwp0[reg] += silu_f(acc0[nt][reg] + bb) * w2;
      cwp1[reg] += silu_f(acc1[nt][reg] + bb) * w2;
    }
  }
#pragma unroll
  for (int reg = 0; reg < 4; reg++) {
    float s0 = cwp0[reg], s1 = cwp1[reg];
    s0 += __shfl_xor(s0, 1); s1 += __shfl_xor(s1, 1);
    s0 += __shfl_xor(s0, 2); s1 += __shfl_xor(s1, 2);
    s0 += __shfl_xor(s0, 4); s1 += __shfl_xor(s1, 4);
    s0 += __shfl_xor(s0, 8); s1 += __shfl_xor(s1, 8);
    cwp0[reg] = s0; cwp1[reg] = s1;
  }
  if (l16 == 0) {
#pragma unroll
    for (int reg = 0; reg < 4; reg++) {
      int row0 = rowBase + quad * 4 + reg;
      int row1 = row0 + 16;
      size_t Ra = (size_t)blk * 128 + row0;
      size_t Rb = (size_t)blk * 128 + row1;
      float inv0 = 1.0f / (dists[row0] + 1e-8f);
      float inv1 = 1.0f / (dists[row1] + 1e-8f);
      float cw0 = cwp0[reg], cw1 = cwp1[reg];
#pragma unroll
      for (int c = 0; c < 3; c++) {
        updv[Ra * 3 + c] = cds[row0 * 3 + c] * inv0 * cw0;
        updv[Rb * 3 + c] = cds[row1 * 3 + c] * inv1 * cw1;
      }
    }
  }
}

// ---------------- node kernel (fused aggregation + x finalize) ----------------
// Layer-1 K=256 = [h (bf16, register-direct) | agg (single-pass CSR gather,
// full 64B lane slice, 2-way unrolled -> 8 loads in flight)]. quad-0 lanes
// also accumulate the signed updv sum for x_out in the same walk.
__global__ __launch_bounds__(256, 4) void node_kernel(
    const float* __restrict__ h, const bf16* __restrict__ hb,
    const bf16* __restrict__ msg, const float* __restrict__ updv,
    const int* __restrict__ offsets, const int* __restrict__ degI,
    const int* __restrict__ adj,
    const bf16* __restrict__ Wn1p, const float* __restrict__ bn1,
    const bf16* __restrict__ Wn2p, const float* __restrict__ bn2,
    const float* __restrict__ x,
    float* __restrict__ hout, float* __restrict__ xout) {
  __shared__ __align__(16) bf16 Tbuf[64 * 128];

  const int tid = threadIdx.x, blk = blockIdx.x;
  const int lane = tid & 63;
  const int quad = lane >> 4, l16 = lane & 15;
  const int rowBase = (tid >> 6) * 16;

  const int Rg = blk * 64 + rowBase + l16;   // batch*NA + atom
  const int atomA = Rg % NA, batA = Rg / NA;
  const int deg = degI[atomA], off = offsets[atomA];
  const bf16* hrow = hb + (size_t)Rg * H;
  const bf16x8* W1v = (const bf16x8*)Wn1p;
  const bf16x8* W2v = (const bf16x8*)Wn2p;

  f32x4 acc[8];
#pragma unroll
  for (int nt = 0; nt < 8; nt++) acc[nt] = (f32x4){0.f, 0.f, 0.f, 0.f};

  // layer-1 first half: h (bf16) register-direct
#pragma unroll
  for (int ks = 0; ks < 4; ks++) {
    bf16x8 a = *(const bf16x8*)(hrow + ks * 32 + quad * 8);
#pragma unroll
    for (int nt = 0; nt < 8; nt++) {
      bf16x8 b = W1v[(nt * 8 + ks) * 64 + lane];
      acc[nt] = __builtin_amdgcn_mfma_f32_16x16x32_bf16(a, b, acc[nt], 0, 0, 0);
    }
  }

  // layer-1 second half: aggregated — single-pass gather, fp32 acc in regs.
  // quad-0 lanes also accumulate the signed updv sum for x_out.
  float a32[32];
#pragma unroll
  for (int t = 0; t < 32; t++) a32[t] = 0.f;
  float sx = 0.f, sy = 0.f, sz = 0.f;
  {
    int j = 0;
    for (; j + 2 <= deg; j += 2) {
      int ent0 = adj[off + j], ent1 = adj[off + j + 1];
      const bf16* m0 = msg + ((size_t)(ent0 >> 1) * 8 + batA) * H + quad * 8;
      const bf16* m1 = msg + ((size_t)(ent1 >> 1) * 8 + batA) * H + quad * 8;
      bf16x8 v0 = *(const bf16x8*)(m0);
      bf16x8 v1 = *(const bf16x8*)(m0 + 32);
      bf16x8 v2 = *(const bf16x8*)(m0 + 64);
      bf16x8 v3 = *(const bf16x8*)(m0 + 96);
      bf16x8 u0 = *(const bf16x8*)(m1);
      bf16x8 u1 = *(const bf16x8*)(m1 + 32);
      bf16x8 u2 = *(const bf16x8*)(m1 + 64);
      bf16x8 u3 = *(const bf16x8*)(m1 + 96);
      if (quad == 0) {
        float sg0 = (ent0 & 1) ? 1.0f : -1.0f;
        float sg1 = (ent1 & 1) ? 1.0f : -1.0f;
        const float* uv0 = updv + ((size_t)(ent0 >> 1) * 8 + batA) * 3;
        const float* uv1 = updv + ((size_t)(ent1 >> 1) * 8 + batA) * 3;
        sx += sg0 * uv0[0] + sg1 * uv1[0];
        sy += sg0 * uv0[1] + sg1 * uv1[1];
        sz += sg0 * uv0[2] + sg1 * uv1[2];
      }
#pragma unroll
      for (int t = 0; t < 8; t++) {
        a32[t]      += (float)v0[t] + (float)u0[t];
        a32[8 + t]  += (float)v1[t] + (float)u1[t];
        a32[16 + t] += (float)v2[t] + (float)u2[t];
        a32[24 + t] += (float)v3[t] + (float)u3[t];
      }
    }
    if (j < deg) {
      int ent0 = adj[off + j];
      const bf16* m0 = msg + ((size_t)(ent0 >> 1) * 8 + batA) * H + quad * 8;
      if (quad == 0) {
        float sg0 = (ent0 & 1) ? 1.0f : -1.0f;
        const float* uv0 = updv + ((size_t)(ent0 >> 1) * 8 + batA) * 3;
        sx += sg0 * uv0[0]; sy += sg0 * uv0[1]; sz += sg0 * uv0[2];
      }
#pragma unroll
      for (int k = 0; k < 4; k++) {
        bf16x8 v = *(const bf16x8*)(m0 + 32 * k);
#pragma unroll
        for (int t = 0; t < 8; t++) a32[8 * k + t] += (float)v[t];
      }
    }
  }

  // x finalize (one lane per row)
  if (quad == 0) {
    float cnt = deg < 1 ? 1.0f : (float)deg;
    float inv = 1.0f / cnt;
    size_t o = (size_t)Rg * 3;
    xout[o + 0] = x[o + 0] + sx * inv;
    xout[o + 1] = x[o + 1] + sy * inv;
    xout[o + 2] = x[o + 2] + sz * inv;
  }

  // MFMA the aggregated half
#pragma unroll
  for (int ks2 = 0; ks2 < 4; ks2++) {
    bf16x8 af;
#pragma unroll
    for (int t = 0; t < 8; t++) af[t] = (bf16)a32[8 * ks2 + t];
#pragma unroll
    for (int nt = 0; nt < 8; nt++) {
      bf16x8 b = W1v[(nt * 8 + 4 + ks2) * 64 + lane];
      acc[nt] = __builtin_amdgcn_mfma_f32_16x16x32_bf16(af, b, acc[nt], 0, 0, 0);
    }
  }
#pragma unroll
  for (int nt = 0; nt < 8; nt++) {
    int col = nt * 16 + l16;
    float bb = bn1[col];
#pragma unroll
    for (int reg = 0; reg < 4; reg++) {
      int row = rowBase + quad * 4 + reg;
      Tbuf[tswz(row, col)] = (bf16)silu_f(acc[nt][reg] + bb);
    }
  }

#pragma unroll
  for (int nt = 0; nt < 8; nt++) acc[nt] = (f32x4){0.f, 0.f, 0.f, 0.f};
#pragma unroll
  for (int ks = 0; ks < 4; ks++) {
    bf16x8 a = *(const bf16x8*)&Tbuf[tswz(rowBase + l16, ks * 32 + quad * 8)];
#pragma unroll
    for (int nt = 0; nt < 8; nt++) {
      bf16x8 b = W2v[(nt * 4 + ks) * 64 + lane];
      acc[nt] = __builtin_amdgcn_mfma_f32_16x16x32_bf16(a, b, acc[nt], 0, 0, 0);
    }
  }
#pragma unroll
  for (int nt = 0; nt < 8; nt++) {
    int col = nt * 16 + l16;
    float bb = bn2[col];
#pragma unroll
    for (int reg = 0; reg < 4; reg++) {
      size_t Ro = (size_t)blk * 64 + rowBase + quad * 4 + reg;
      hout[Ro * H + col] = h[Ro * H + col] + acc[nt][reg] + bb;
    }
  }
}

extern "C" void kernel_launch(void* const* d_in, const int* in_sizes, int n_in,
                              void* d_out, int out_size, void* d_ws,
                              size_t ws_size, hipStream_t stream) {
  const float* h    = (const float*)d_in[0];
  const float* x    = (const float*)d_in[1];
  const int*  bonds = (const int*)d_in[2];
  const float* Wm1  = (const float*)d_in[3];
  const float* bm1  = (const float*)d_in[4];
  const float* Wm2  = (const float*)d_in[5];
  const float* bm2  = (const float*)d_in[6];
  const float* Wn1  = (const float*)d_in[7];
  const float* bn1  = (const float*)d_in[8];
  const float* Wn2  = (const float*)d_in[9];
  const float* bn2  = (const float*)d_in[10];
  const float* Wc1  = (const float*)d_in[11];
  const float* bc1  = (const float*)d_in[12];
  const float* Wc2  = (const float*)d_in[13];

  float* out  = (float*)d_out;
  float* hout = out;
  float* xout = out + (size_t)NBATCH * NA * H;

  char* ws = (char*)d_ws;
  // layout (bytes): NEED = 170,655,744 < 173,080,576 proven available.
  const size_t OFF_DEG  = 0;                        // NA int
  const size_t OFF_OFFS = 81920;                    // NA int
  const size_t OFF_CUR  = 163840;                   // NA int
  const size_t OFF_ADJ  = 245760;                   // 2*NB int = 480,000 B
  const size_t OFF_W1   = 786432;                   // 65,536 B
  const size_t OFF_W2   = OFF_W1 + 65536;           // 32,768
  const size_t OFF_WN1  = OFF_W2 + 32768;           // 65,536
  const size_t OFF_WN2  = OFF_WN1 + 65536;          // 32,768
  const size_t OFF_WC1  = OFF_WN2 + 32768;          // 32,768 (ends 1,015,808)
  const size_t OFF_UPDV = 1048576;                  // NB*8*3 f32 = 5,760,000
  const size_t OFF_HB   = 6815744;                  // 160000*128 bf16 = 40,960,000
  const size_t OFF_MSG  = 47775744;                 // NB*8*128 bf16 = 122,880,000

  int*   degI = (int*)(ws + OFF_DEG);
  int*   offs = (int*)(ws + OFF_OFFS);
  int*   cur  = (int*)(ws + OFF_CUR);
  int*   adj  = (int*)(ws + OFF_ADJ);
  bf16*  W1p  = (bf16*)(ws + OFF_W1);
  bf16*  W2p  = (bf16*)(ws + OFF_W2);
  bf16*  Wn1p = (bf16*)(ws + OFF_WN1);
  bf16*  Wn2p = (bf16*)(ws + OFF_WN2);
  bf16*  Wc1p = (bf16*)(ws + OFF_WC1);
  float* updv = (float*)(ws + OFF_UPDV);
  bf16*  hb   = (bf16*)(ws + OFF_HB);
  bf16*  msgB = (bf16*)(ws + OFF_MSG);

  (void)hipMemsetAsync(degI, 0, NA * sizeof(int), stream);
  (void)hipMemsetAsync(cur, 0, NA * sizeof(int), stream);

  cast_h<<<NBATCH * NA * H / 1024, 256, 0, stream>>>(h, hb);
  pack_w<<<128, 256, 0, stream>>>(Wm1, W1p, 256);
  pack_w<<<64, 256, 0, stream>>>(Wm2, W2p, 128);
  pack_w<<<128, 256, 0, stream>>>(Wn1, Wn1p, 256);
  pack_w<<<64, 256, 0, stream>>>(Wn2, Wn2p, 128);
  pack_w<<<64, 256, 0, stream>>>(Wc1, Wc1p, 128);

  count_deg<<<(NB + 255) / 256, 256, 0, stream>>>(bonds, degI);
  scan_offsets<<<1, 1024, 0, stream>>>(degI, offs);
  build_adj<<<(NB + 255) / 256, 256, 0, stream>>>(bonds, offs, cur, adj);

  msg_kernel<<<NB * NBATCH / 128, 256, 0, stream>>>(
      hb, x, bonds, W1p, bm1, W2p, bm2, Wm1 + 256 * H, Wc1p, bc1, Wc2,
      msgB, updv);
  node_kernel<<<NBATCH * NA / 64, 256, 0, stream>>>(
      h, hb, msgB, updv, offs, degI, adj, Wn1p, bn1, Wn2p, bn2, x,
      hout, xout);
}

// Round 4
// 581.473 us; speedup vs baseline: 1.0932x; 1.0932x over previous
//
#include <hip/hip_runtime.h>

// BondAwareEGNN fused layer — round 9.
//
// Round-8 post-mortem: M=32/wave spilled (WRITE 133->403MB, FETCH
// 160->325MB; acc0+acc1=64 AGPR + ~64 VGPR hit the 128 cap) — B-reuse
// win canceled by scratch traffic, dur unchanged 263us. r6+r8 agree:
// the kernel is latency-bound at 4 waves/SIMD and needs MORE WAVES,
// which requires a true <=64-reg wave.
//
// Round-9: N-SPLIT. Each wave: 16 rows x 64 cols -> acc[4] = 16 AGPR
// (the only large state). Block = 32 rows (2 row-grp x 2 col-grp).
// __launch_bounds__(256,8): 8 waves/SIMD, genuinely fits. Costs: rows
// shared by 2 waves -> 4 barriers/block; coord-head scalar combined
// across col-waves via LDS cwpart. LDS ~11.5KB (not the cap). B-loads
// per wave halve. Spill detector: WRITE_SIZE must stay ~133MB.
// Node kernel unchanged.

#define H      128
#define NA     20000
#define NB     60000
#define NBATCH 8

typedef __bf16 bf16;
typedef __bf16 bf16x4 __attribute__((ext_vector_type(4)));
typedef __bf16 bf16x8 __attribute__((ext_vector_type(8)));
typedef float  f32x4  __attribute__((ext_vector_type(4)));

__device__ __forceinline__ float silu_f(float v) {
  float e = __expf(-v);
  return v * __builtin_amdgcn_rcpf(1.0f + e);  // 1-ulp rcp; inf -> 0 ok
}

// XOR-swizzled index into a [R][128] bf16 tile. Row stride 256B (bank
// neutral); 16B chunk index XOR'd with row&7 rotates banks. Bijective per
// row; 8-element chunks stay contiguous so bf16x8 loads/stores still work.
__device__ __forceinline__ int tswz(int row, int col) {
  return (row << 7) + (((((col) >> 3) ^ (row & 7)) << 3) | (col & 7));
}

__global__ void cast_h(const float* __restrict__ src, bf16* __restrict__ dst) {
  int i = blockIdx.x * 256 + threadIdx.x;  // one float4 per thread
  float4 v = *(const float4*)(src + (size_t)i * 4);
  bf16x4 t = {(bf16)v.x, (bf16)v.y, (bf16)v.z, (bf16)v.w};
  *(bf16x4*)(dst + (size_t)i * 4) = t;
}

// fp32 KxN(128) row-major -> bf16 fragment-linear (8 bf16 per lane-frag).
__global__ void pack_w(const float* __restrict__ src, bf16* __restrict__ dst,
                       int K) {
  int i = blockIdx.x * 256 + threadIdx.x;
  if (i >= K * 128) return;
  int k = i >> 7, n = i & 127;
  int nt = n >> 4, ks = k >> 5;
  int lane = (((k >> 3) & 3) << 4) | (n & 15);
  int j = k & 7;
  int KS = K >> 5;
  dst[((((nt * KS + ks) * 64) + lane) << 3) + j] = (bf16)src[i];
}

// ---------------- CSR build ----------------
__global__ void count_deg(const int* __restrict__ bonds,
                          int* __restrict__ degI) {
  int e = blockIdx.x * 256 + threadIdx.x;
  if (e >= NB) return;
  atomicAdd(&degI[bonds[2 * e]], 1);
  atomicAdd(&degI[bonds[2 * e + 1]], 1);
}

// single block, 1024 threads, wave-shfl scan (4 barriers per 1024-chunk)
__global__ void scan_offsets(const int* __restrict__ deg,
                             int* __restrict__ offsets) {
  __shared__ int wsum[16];
  __shared__ int carry;
  const int tid = threadIdx.x;
  const int wave = tid >> 6, lane = tid & 63;
  if (tid == 0) carry = 0;
  __syncthreads();
  for (int base = 0; base < NA; base += 1024) {
    int i = base + tid;
    int v = (i < NA) ? deg[i] : 0;
    int s = v;  // inclusive scan within wave
#pragma unroll
    for (int o = 1; o < 64; o <<= 1) {
      int t = __shfl_up(s, o);
      if (lane >= o) s += t;
    }
    if (lane == 63) wsum[wave] = s;
    __syncthreads();
    if (wave == 0) {  // scan the 16 wave totals
      int w = (lane < 16) ? wsum[lane] : 0;
#pragma unroll
      for (int o = 1; o < 16; o <<= 1) {
        int t = __shfl_up(w, o);
        if (lane >= o) w += t;
      }
      if (lane < 16) wsum[lane] = w;  // inclusive
    }
    __syncthreads();
    int pre = carry + (wave > 0 ? wsum[wave - 1] : 0);
    if (i < NA) offsets[i] = pre + s - v;  // exclusive
    __syncthreads();
    if (tid == 0) carry += wsum[15];
    __syncthreads();
  }
}

__global__ void build_adj(const int* __restrict__ bonds,
                          const int* __restrict__ offsets,
                          int* __restrict__ cursor, int* __restrict__ adj) {
  int e = blockIdx.x * 256 + threadIdx.x;
  if (e >= NB) return;
  int s = bonds[2 * e], d = bonds[2 * e + 1];
  int p = atomicAdd(&cursor[s], 1);
  adj[offsets[s] + p] = (e << 1);        // src endpoint (coord sign -)
  p = atomicAdd(&cursor[d], 1);
  adj[offsets[d] + p] = (e << 1) | 1;    // dst endpoint (coord sign +)
}

// ---------------- message kernel (N-split: 16 rows x 64 cols per wave) ----
__global__ __launch_bounds__(256, 8) void msg_kernel(
    const bf16* __restrict__ hb, const float* __restrict__ x,
    const int* __restrict__ bonds,
    const bf16* __restrict__ W1p, const float* __restrict__ bm1,
    const bf16* __restrict__ W2p, const float* __restrict__ bm2,
    const float* __restrict__ w1c,   // Wm1 row 256 (dist row), fp32[128]
    const bf16* __restrict__ Wc1p, const float* __restrict__ bc1,
    const float* __restrict__ Wc2,
    bf16* __restrict__ msgOut, float* __restrict__ updv) {
  // [32][128] swizzled tile: T after layer-1, messages after layer-2.
  __shared__ __align__(16) bf16 Tbuf[32 * 128];
  __shared__ float cds[32 * 3];
  __shared__ float dists[32];
  __shared__ float bm1s[128], bm2s[128], w1cs[128], bc1s[128], wc2s[128];
  __shared__ float cwpart[2][32];

  const int tid = threadIdx.x, blk = blockIdx.x;

  if (tid < 32) {
    int Rg = blk * 32 + tid;
    int bond = Rg >> 3, batch = Rg & 7;
    int s = bonds[2 * bond], dn = bonds[2 * bond + 1];
    const float* xs = x + (size_t)(batch * NA + s) * 3;
    const float* xd = x + (size_t)(batch * NA + dn) * 3;
    float c0 = xd[0] - xs[0], c1 = xd[1] - xs[1], c2 = xd[2] - xs[2];
    cds[tid * 3 + 0] = c0; cds[tid * 3 + 1] = c1; cds[tid * 3 + 2] = c2;
    dists[tid] = sqrtf(c0 * c0 + c1 * c1 + c2 * c2);
  }
  if (tid < 128) {
    bm1s[tid] = bm1[tid]; bm2s[tid] = bm2[tid]; w1cs[tid] = w1c[tid];
    bc1s[tid] = bc1[tid]; wc2s[tid] = Wc2[tid];
  }
  __syncthreads();

  const int lane = tid & 63;
  const int quad = lane >> 4, l16 = lane & 15;
  const int wave = tid >> 6;
  const int rowBase = (wave >> 1) * 16;    // 2 row-groups
  const int colG = wave & 1;               // 2 col-groups
  const int colBase = colG * 64;
  const bf16x8* W1v = (const bf16x8*)W1p;
  const bf16x8* W2v = (const bf16x8*)W2p;
  const bf16x8* Wc1v = (const bf16x8*)Wc1p;

  // per-lane A-row metadata (row = rowBase + l16)
  const int RgA = blk * 32 + rowBase + l16;
  const int bondA = RgA >> 3, batA = RgA & 7;
  const bf16* hsrc = hb + (size_t)(batA * NA + bonds[2 * bondA]) * H;
  const bf16* hdst = hb + (size_t)(batA * NA + bonds[2 * bondA + 1]) * H;

  f32x4 acc[4];
#pragma unroll
  for (int nt = 0; nt < 4; nt++) acc[nt] = (f32x4){0.f, 0.f, 0.f, 0.f};

  // ---- layer 1: K = 256, A straight from global, B = this wave's W half --
#pragma unroll
  for (int ks = 0; ks < 4; ks++) {
    bf16x8 a = *(const bf16x8*)(hsrc + ks * 32 + quad * 8);
#pragma unroll
    for (int nt = 0; nt < 4; nt++) {
      bf16x8 b = W1v[((colG * 4 + nt) * 8 + ks) * 64 + lane];
      acc[nt] = __builtin_amdgcn_mfma_f32_16x16x32_bf16(a, b, acc[nt], 0, 0, 0);
    }
  }
#pragma unroll
  for (int ks = 4; ks < 8; ks++) {
    bf16x8 a = *(const bf16x8*)(hdst + (ks - 4) * 32 + quad * 8);
#pragma unroll
    for (int nt = 0; nt < 4; nt++) {
      bf16x8 b = W1v[((colG * 4 + nt) * 8 + ks) * 64 + lane];
      acc[nt] = __builtin_amdgcn_mfma_f32_16x16x32_bf16(a, b, acc[nt], 0, 0, 0);
    }
  }
  // t1 epilogue -> Tbuf
#pragma unroll
  for (int nt = 0; nt < 4; nt++) {
    int col = colBase + nt * 16 + l16;
    float bb = bm1s[col], wc = w1cs[col];
#pragma unroll
    for (int reg = 0; reg < 4; reg++) {
      int row = rowBase + quad * 4 + reg;
      float v = acc[nt][reg] + bb + dists[row] * wc;
      Tbuf[tswz(row, col)] = (bf16)silu_f(v);
    }
  }
  __syncthreads();   // T complete (both col halves)

  // ---- layer 2: K = 128 -> messages ----
#pragma unroll
  for (int nt = 0; nt < 4; nt++) acc[nt] = (f32x4){0.f, 0.f, 0.f, 0.f};
#pragma unroll
  for (int ks = 0; ks < 4; ks++) {
    bf16x8 a = *(const bf16x8*)&Tbuf[tswz(rowBase + l16, ks * 32 + quad * 8)];
#pragma unroll
    for (int nt = 0; nt < 4; nt++) {
      bf16x8 b = W2v[((colG * 4 + nt) * 4 + ks) * 64 + lane];
      acc[nt] = __builtin_amdgcn_mfma_f32_16x16x32_bf16(a, b, acc[nt], 0, 0, 0);
    }
  }
  __syncthreads();   // all layer-2 reads of T done; safe to overwrite
#pragma unroll
  for (int nt = 0; nt < 4; nt++) {
    int col = colBase + nt * 16 + l16;
    float bb = bm2s[col];
#pragma unroll
    for (int reg = 0; reg < 4; reg++) {
      int row = rowBase + quad * 4 + reg;
      Tbuf[tswz(row, col)] = (bf16)silu_f(acc[nt][reg] + bb);
    }
  }
  __syncthreads();   // messages complete

  // ---- coord head: silu(messages @ Wc1 + bc1) @ Wc2 ----
#pragma unroll
  for (int nt = 0; nt < 4; nt++) acc[nt] = (f32x4){0.f, 0.f, 0.f, 0.f};
#pragma unroll
  for (int ks = 0; ks < 4; ks++) {
    bf16x8 a = *(const bf16x8*)&Tbuf[tswz(rowBase + l16, ks * 32 + quad * 8)];
#pragma unroll
    for (int nt = 0; nt < 4; nt++) {
      bf16x8 b = Wc1v[((colG * 4 + nt) * 4 + ks) * 64 + lane];
      acc[nt] = __builtin_amdgcn_mfma_f32_16x16x32_bf16(a, b, acc[nt], 0, 0, 0);
    }
  }

  // copy this wave's 16 rows x 64 cols of messages to global (16B chunks)
#pragma unroll
  for (int i = 0; i < 2; i++) {
    int item = i * 64 + lane;
    int row = rowBase + (item >> 3);
    int cg = colG * 8 + (item & 7);
    *(bf16x8*)&msgOut[(size_t)(blk * 32 + row) * H + cg * 8] =
        *(const bf16x8*)&Tbuf[tswz(row, cg * 8)];
  }

  float cwp[4] = {0.f, 0.f, 0.f, 0.f};
#pragma unroll
  for (int nt = 0; nt < 4; nt++) {
    int col = colBase + nt * 16 + l16;
    float bb = bc1s[col], w2 = wc2s[col];
#pragma unroll
    for (int reg = 0; reg < 4; reg++)
      cwp[reg] += silu_f(acc[nt][reg] + bb) * w2;
  }
#pragma unroll
  for (int reg = 0; reg < 4; reg++) {
    float s = cwp[reg];
    s += __shfl_xor(s, 1);
    s += __shfl_xor(s, 2);
    s += __shfl_xor(s, 4);
    s += __shfl_xor(s, 8);
    cwp[reg] = s;
  }
  if (l16 == 0) {
#pragma unroll
    for (int reg = 0; reg < 4; reg++)
      cwpart[colG][rowBase + quad * 4 + reg] = cwp[reg];
  }
  __syncthreads();   // both col-halves' partials in
  if (colG == 0 && l16 == 0) {
#pragma unroll
    for (int reg = 0; reg < 4; reg++) {
      int row = rowBase + quad * 4 + reg;
      size_t Rg = (size_t)blk * 32 + row;
      float cw = cwpart[0][row] + cwpart[1][row];
      float inv = 1.0f / (dists[row] + 1e-8f);
#pragma unroll
      for (int c = 0; c < 3; c++)
        updv[Rg * 3 + c] = cds[row * 3 + c] * inv * cw;
    }
  }
}

// ---------------- node kernel (fused aggregation + x finalize) ----------------
// Layer-1 K=256 = [h (bf16, register-direct) | agg (single-pass CSR gather,
// full 64B lane slice, 2-way unrolled -> 8 loads in flight)]. quad-0 lanes
// also accumulate the signed updv sum for x_out in the same walk.
__global__ __launch_bounds__(256, 4) void node_kernel(
    const float* __restrict__ h, const bf16* __restrict__ hb,
    const bf16* __restrict__ msg, const float* __restrict__ updv,
    const int* __restrict__ offsets, const int* __restrict__ degI,
    const int* __restrict__ adj,
    const bf16* __restrict__ Wn1p, const float* __restrict__ bn1,
    const bf16* __restrict__ Wn2p, const float* __restrict__ bn2,
    const float* __restrict__ x,
    float* __restrict__ hout, float* __restrict__ xout) {
  __shared__ __align__(16) bf16 Tbuf[64 * 128];

  const int tid = threadIdx.x, blk = blockIdx.x;
  const int lane = tid & 63;
  const int quad = lane >> 4, l16 = lane & 15;
  const int rowBase = (tid >> 6) * 16;

  const int Rg = blk * 64 + rowBase + l16;   // batch*NA + atom
  const int atomA = Rg % NA, batA = Rg / NA;
  const int deg = degI[atomA], off = offsets[atomA];
  const bf16* hrow = hb + (size_t)Rg * H;
  const bf16x8* W1v = (const bf16x8*)Wn1p;
  const bf16x8* W2v = (const bf16x8*)Wn2p;

  f32x4 acc[8];
#pragma unroll
  for (int nt = 0; nt < 8; nt++) acc[nt] = (f32x4){0.f, 0.f, 0.f, 0.f};

  // layer-1 first half: h (bf16) register-direct
#pragma unroll
  for (int ks = 0; ks < 4; ks++) {
    bf16x8 a = *(const bf16x8*)(hrow + ks * 32 + quad * 8);
#pragma unroll
    for (int nt = 0; nt < 8; nt++) {
      bf16x8 b = W1v[(nt * 8 + ks) * 64 + lane];
      acc[nt] = __builtin_amdgcn_mfma_f32_16x16x32_bf16(a, b, acc[nt], 0, 0, 0);
    }
  }

  // layer-1 second half: aggregated — single-pass gather, fp32 acc in regs.
  // quad-0 lanes also accumulate the signed updv sum for x_out.
  float a32[32];
#pragma unroll
  for (int t = 0; t < 32; t++) a32[t] = 0.f;
  float sx = 0.f, sy = 0.f, sz = 0.f;
  {
    int j = 0;
    for (; j + 2 <= deg; j += 2) {
      int ent0 = adj[off + j], ent1 = adj[off + j + 1];
      const bf16* m0 = msg + ((size_t)(ent0 >> 1) * 8 + batA) * H + quad * 8;
      const bf16* m1 = msg + ((size_t)(ent1 >> 1) * 8 + batA) * H + quad * 8;
      bf16x8 v0 = *(const bf16x8*)(m0);
      bf16x8 v1 = *(const bf16x8*)(m0 + 32);
      bf16x8 v2 = *(const bf16x8*)(m0 + 64);
      bf16x8 v3 = *(const bf16x8*)(m0 + 96);
      bf16x8 u0 = *(const bf16x8*)(m1);
      bf16x8 u1 = *(const bf16x8*)(m1 + 32);
      bf16x8 u2 = *(const bf16x8*)(m1 + 64);
      bf16x8 u3 = *(const bf16x8*)(m1 + 96);
      if (quad == 0) {
        float sg0 = (ent0 & 1) ? 1.0f : -1.0f;
        float sg1 = (ent1 & 1) ? 1.0f : -1.0f;
        const float* uv0 = updv + ((size_t)(ent0 >> 1) * 8 + batA) * 3;
        const float* uv1 = updv + ((size_t)(ent1 >> 1) * 8 + batA) * 3;
        sx += sg0 * uv0[0] + sg1 * uv1[0];
        sy += sg0 * uv0[1] + sg1 * uv1[1];
        sz += sg0 * uv0[2] + sg1 * uv1[2];
      }
#pragma unroll
      for (int t = 0; t < 8; t++) {
        a32[t]      += (float)v0[t] + (float)u0[t];
        a32[8 + t]  += (float)v1[t] + (float)u1[t];
        a32[16 + t] += (float)v2[t] + (float)u2[t];
        a32[24 + t] += (float)v3[t] + (float)u3[t];
      }
    }
    if (j < deg) {
      int ent0 = adj[off + j];
      const bf16* m0 = msg + ((size_t)(ent0 >> 1) * 8 + batA) * H + quad * 8;
      if (quad == 0) {
        float sg0 = (ent0 & 1) ? 1.0f : -1.0f;
        const float* uv0 = updv + ((size_t)(ent0 >> 1) * 8 + batA) * 3;
        sx += sg0 * uv0[0]; sy += sg0 * uv0[1]; sz += sg0 * uv0[2];
      }
#pragma unroll
      for (int k = 0; k < 4; k++) {
        bf16x8 v = *(const bf16x8*)(m0 + 32 * k);
#pragma unroll
        for (int t = 0; t < 8; t++) a32[8 * k + t] += (float)v[t];
      }
    }
  }

  // x finalize (one lane per row)
  if (quad == 0) {
    float cnt = deg < 1 ? 1.0f : (float)deg;
    float inv = 1.0f / cnt;
    size_t o = (size_t)Rg * 3;
    xout[o + 0] = x[o + 0] + sx * inv;
    xout[o + 1] = x[o + 1] + sy * inv;
    xout[o + 2] = x[o + 2] + sz * inv;
  }

  // MFMA the aggregated half
#pragma unroll
  for (int ks2 = 0; ks2 < 4; ks2++) {
    bf16x8 af;
#pragma unroll
    for (int t = 0; t < 8; t++) af[t] = (bf16)a32[8 * ks2 + t];
#pragma unroll
    for (int nt = 0; nt < 8; nt++) {
      bf16x8 b = W1v[(nt * 8 + 4 + ks2) * 64 + lane];
      acc[nt] = __builtin_amdgcn_mfma_f32_16x16x32_bf16(af, b, acc[nt], 0, 0, 0);
    }
  }
#pragma unroll
  for (int nt = 0; nt < 8; nt++) {
    int col = nt * 16 + l16;
    float bb = bn1[col];
#pragma unroll
    for (int reg = 0; reg < 4; reg++) {
      int row = rowBase + quad * 4 + reg;
      Tbuf[tswz(row, col)] = (bf16)silu_f(acc[nt][reg] + bb);
    }
  }

#pragma unroll
  for (int nt = 0; nt < 8; nt++) acc[nt] = (f32x4){0.f, 0.f, 0.f, 0.f};
#pragma unroll
  for (int ks = 0; ks < 4; ks++) {
    bf16x8 a = *(const bf16x8*)&Tbuf[tswz(rowBase + l16, ks * 32 + quad * 8)];
#pragma unroll
    for (int nt = 0; nt < 8; nt++) {
      bf16x8 b = W2v[(nt * 4 + ks) * 64 + lane];
      acc[nt] = __builtin_amdgcn_mfma_f32_16x16x32_bf16(a, b, acc[nt], 0, 0, 0);
    }
  }
#pragma unroll
  for (int nt = 0; nt < 8; nt++) {
    int col = nt * 16 + l16;
    float bb = bn2[col];
#pragma unroll
    for (int reg = 0; reg < 4; reg++) {
      size_t Ro = (size_t)blk * 64 + rowBase + quad * 4 + reg;
      hout[Ro * H + col] = h[Ro * H + col] + acc[nt][reg] + bb;
    }
  }
}

extern "C" void kernel_launch(void* const* d_in, const int* in_sizes, int n_in,
                              void* d_out, int out_size, void* d_ws,
                              size_t ws_size, hipStream_t stream) {
  const float* h    = (const float*)d_in[0];
  const float* x    = (const float*)d_in[1];
  const int*  bonds = (const int*)d_in[2];
  const float* Wm1  = (const float*)d_in[3];
  const float* bm1  = (const float*)d_in[4];
  const float* Wm2  = (const float*)d_in[5];
  const float* bm2  = (const float*)d_in[6];
  const float* Wn1  = (const float*)d_in[7];
  const float* bn1  = (const float*)d_in[8];
  const float* Wn2  = (const float*)d_in[9];
  const float* bn2  = (const float*)d_in[10];
  const float* Wc1  = (const float*)d_in[11];
  const float* bc1  = (const float*)d_in[12];
  const float* Wc2  = (const float*)d_in[13];

  float* out  = (float*)d_out;
  float* hout = out;
  float* xout = out + (size_t)NBATCH * NA * H;

  char* ws = (char*)d_ws;
  // layout (bytes): NEED = 170,655,744 < 173,080,576 proven available.
  const size_t OFF_DEG  = 0;                        // NA int
  const size_t OFF_OFFS = 81920;                    // NA int
  const size_t OFF_CUR  = 163840;                   // NA int
  const size_t OFF_ADJ  = 245760;                   // 2*NB int = 480,000 B
  const size_t OFF_W1   = 786432;                   // 65,536 B
  const size_t OFF_W2   = OFF_W1 + 65536;           // 32,768
  const size_t OFF_WN1  = OFF_W2 + 32768;           // 65,536
  const size_t OFF_WN2  = OFF_WN1 + 65536;          // 32,768
  const size_t OFF_WC1  = OFF_WN2 + 32768;          // 32,768 (ends 1,015,808)
  const size_t OFF_UPDV = 1048576;                  // NB*8*3 f32 = 5,760,000
  const size_t OFF_HB   = 6815744;                  // 160000*128 bf16 = 40,960,000
  const size_t OFF_MSG  = 47775744;                 // NB*8*128 bf16 = 122,880,000

  int*   degI = (int*)(ws + OFF_DEG);
  int*   offs = (int*)(ws + OFF_OFFS);
  int*   cur  = (int*)(ws + OFF_CUR);
  int*   adj  = (int*)(ws + OFF_ADJ);
  bf16*  W1p  = (bf16*)(ws + OFF_W1);
  bf16*  W2p  = (bf16*)(ws + OFF_W2);
  bf16*  Wn1p = (bf16*)(ws + OFF_WN1);
  bf16*  Wn2p = (bf16*)(ws + OFF_WN2);
  bf16*  Wc1p = (bf16*)(ws + OFF_WC1);
  float* updv = (float*)(ws + OFF_UPDV);
  bf16*  hb   = (bf16*)(ws + OFF_HB);
  bf16*  msgB = (bf16*)(ws + OFF_MSG);

  (void)hipMemsetAsync(degI, 0, NA * sizeof(int), stream);
  (void)hipMemsetAsync(cur, 0, NA * sizeof(int), stream);

  cast_h<<<NBATCH * NA * H / 1024, 256, 0, stream>>>(h, hb);
  pack_w<<<128, 256, 0, stream>>>(Wm1, W1p, 256);
  pack_w<<<64, 256, 0, stream>>>(Wm2, W2p, 128);
  pack_w<<<128, 256, 0, stream>>>(Wn1, Wn1p, 256);
  pack_w<<<64, 256, 0, stream>>>(Wn2, Wn2p, 128);
  pack_w<<<64, 256, 0, stream>>>(Wc1, Wc1p, 128);

  count_deg<<<(NB + 255) / 256, 256, 0, stream>>>(bonds, degI);
  scan_offsets<<<1, 1024, 0, stream>>>(degI, offs);
  build_adj<<<(NB + 255) / 256, 256, 0, stream>>>(bonds, offs, cur, adj);

  msg_kernel<<<NB * NBATCH / 32, 256, 0, stream>>>(
      hb, x, bonds, W1p, bm1, W2p, bm2, Wm1 + 256 * H, Wc1p, bc1, Wc2,
      msgB, updv);
  node_kernel<<<NBATCH * NA / 64, 256, 0, stream>>>(
      h, hb, msgB, updv, offs, degI, adj, Wn1p, bn1, Wn2p, bn2, x,
      hout, xout);
}

// Round 5
// 508.208 us; speedup vs baseline: 1.2508x; 1.1442x over previous
//
#include <hip/hip_runtime.h>

// BondAwareEGNN fused layer — round 10.
//
// Round-9 post-mortem: N-split worked (occ 43->83%, dur 263->218) but
// (256,8)'s 64-reg cap STILL spilled ~110MB (WRITE 245 vs 133 ideal,
// VGPR_Count=32 = squeezed-allocator signature).
//
// Round-10 changes:
//   1. msg: __launch_bounds__(256,6) — cap ~85 regs. Kernel needs
//      ~55-70; allocator stops spilling, HW still grants 7-8 waves/SIMD.
//   2. node: N-split port. Phase 1 = block-wide coalesced gather
//      (thread = row x 32B chunk, 8 threads cover a 256B msg row,
//      2-way unroll) -> LDS agg tile + fused x_out. Phase 2 = 16x64
//      MFMA waves, acc[4] (~50 regs -> 8 waves/SIMD). 2 barriers.
//   3. CSR: fixed-capacity slot build adj2[atom][32] in ONE kernel —
//      removes count_deg + single-block serial scan (+~40us).

#define H      128
#define NA     20000
#define NB     60000
#define NBATCH 8
#define ADJ_CAP 32

typedef __bf16 bf16;
typedef __bf16 bf16x4 __attribute__((ext_vector_type(4)));
typedef __bf16 bf16x8 __attribute__((ext_vector_type(8)));
typedef float  f32x4  __attribute__((ext_vector_type(4)));

__device__ __forceinline__ float silu_f(float v) {
  float e = __expf(-v);
  return v * __builtin_amdgcn_rcpf(1.0f + e);  // 1-ulp rcp; inf -> 0 ok
}

// XOR-swizzled index into a [R][128] bf16 tile. Row stride 256B (bank
// neutral); 16B chunk index XOR'd with row&7 rotates banks. Bijective per
// row; 8-element chunks stay contiguous so bf16x8 loads/stores still work.
__device__ __forceinline__ int tswz(int row, int col) {
  return (row << 7) + (((((col) >> 3) ^ (row & 7)) << 3) | (col & 7));
}

__global__ void cast_h(const float* __restrict__ src, bf16* __restrict__ dst) {
  int i = blockIdx.x * 256 + threadIdx.x;  // one float4 per thread
  float4 v = *(const float4*)(src + (size_t)i * 4);
  bf16x4 t = {(bf16)v.x, (bf16)v.y, (bf16)v.z, (bf16)v.w};
  *(bf16x4*)(dst + (size_t)i * 4) = t;
}

// fp32 KxN(128) row-major -> bf16 fragment-linear (8 bf16 per lane-frag).
__global__ void pack_w(const float* __restrict__ src, bf16* __restrict__ dst,
                       int K) {
  int i = blockIdx.x * 256 + threadIdx.x;
  if (i >= K * 128) return;
  int k = i >> 7, n = i & 127;
  int nt = n >> 4, ks = k >> 5;
  int lane = (((k >> 3) & 3) << 4) | (n & 15);
  int j = k & 7;
  int KS = K >> 5;
  dst[((((nt * KS + ks) * 64) + lane) << 3) + j] = (bf16)src[i];
}

// ---------------- adjacency build (fixed-capacity slots) ----------------
// degI doubles as the slot cursor; max deg for this input << ADJ_CAP.
__global__ void build_adj2(const int* __restrict__ bonds,
                           int* __restrict__ degI, int* __restrict__ adj2) {
  int e = blockIdx.x * 256 + threadIdx.x;
  if (e >= NB) return;
  int s = bonds[2 * e], d = bonds[2 * e + 1];
  int p = atomicAdd(&degI[s], 1);
  if (p < ADJ_CAP) adj2[s * ADJ_CAP + p] = (e << 1);        // src: sign -
  p = atomicAdd(&degI[d], 1);
  if (p < ADJ_CAP) adj2[d * ADJ_CAP + p] = (e << 1) | 1;    // dst: sign +
}

// ---------------- message kernel (N-split: 16 rows x 64 cols per wave) ----
__global__ __launch_bounds__(256, 6) void msg_kernel(
    const bf16* __restrict__ hb, const float* __restrict__ x,
    const int* __restrict__ bonds,
    const bf16* __restrict__ W1p, const float* __restrict__ bm1,
    const bf16* __restrict__ W2p, const float* __restrict__ bm2,
    const float* __restrict__ w1c,   // Wm1 row 256 (dist row), fp32[128]
    const bf16* __restrict__ Wc1p, const float* __restrict__ bc1,
    const float* __restrict__ Wc2,
    bf16* __restrict__ msgOut, float* __restrict__ updv) {
  // [32][128] swizzled tile: T after layer-1, messages after layer-2.
  __shared__ __align__(16) bf16 Tbuf[32 * 128];
  __shared__ float cds[32 * 3];
  __shared__ float dists[32];
  __shared__ float bm1s[128], bm2s[128], w1cs[128], bc1s[128], wc2s[128];
  __shared__ float cwpart[2][32];

  const int tid = threadIdx.x, blk = blockIdx.x;

  if (tid < 32) {
    int Rg = blk * 32 + tid;
    int bond = Rg >> 3, batch = Rg & 7;
    int s = bonds[2 * bond], dn = bonds[2 * bond + 1];
    const float* xs = x + (size_t)(batch * NA + s) * 3;
    const float* xd = x + (size_t)(batch * NA + dn) * 3;
    float c0 = xd[0] - xs[0], c1 = xd[1] - xs[1], c2 = xd[2] - xs[2];
    cds[tid * 3 + 0] = c0; cds[tid * 3 + 1] = c1; cds[tid * 3 + 2] = c2;
    dists[tid] = sqrtf(c0 * c0 + c1 * c1 + c2 * c2);
  }
  if (tid < 128) {
    bm1s[tid] = bm1[tid]; bm2s[tid] = bm2[tid]; w1cs[tid] = w1c[tid];
    bc1s[tid] = bc1[tid]; wc2s[tid] = Wc2[tid];
  }
  __syncthreads();

  const int lane = tid & 63;
  const int quad = lane >> 4, l16 = lane & 15;
  const int wave = tid >> 6;
  const int rowBase = (wave >> 1) * 16;    // 2 row-groups
  const int colG = wave & 1;               // 2 col-groups
  const int colBase = colG * 64;
  const bf16x8* W1v = (const bf16x8*)W1p;
  const bf16x8* W2v = (const bf16x8*)W2p;
  const bf16x8* Wc1v = (const bf16x8*)Wc1p;

  // per-lane A-row metadata (row = rowBase + l16)
  const int RgA = blk * 32 + rowBase + l16;
  const int bondA = RgA >> 3, batA = RgA & 7;
  const bf16* hsrc = hb + (size_t)(batA * NA + bonds[2 * bondA]) * H;
  const bf16* hdst = hb + (size_t)(batA * NA + bonds[2 * bondA + 1]) * H;

  f32x4 acc[4];
#pragma unroll
  for (int nt = 0; nt < 4; nt++) acc[nt] = (f32x4){0.f, 0.f, 0.f, 0.f};

  // ---- layer 1: K = 256, A straight from global, B = this wave's W half --
#pragma unroll
  for (int ks = 0; ks < 4; ks++) {
    bf16x8 a = *(const bf16x8*)(hsrc + ks * 32 + quad * 8);
#pragma unroll
    for (int nt = 0; nt < 4; nt++) {
      bf16x8 b = W1v[((colG * 4 + nt) * 8 + ks) * 64 + lane];
      acc[nt] = __builtin_amdgcn_mfma_f32_16x16x32_bf16(a, b, acc[nt], 0, 0, 0);
    }
  }
#pragma unroll
  for (int ks = 4; ks < 8; ks++) {
    bf16x8 a = *(const bf16x8*)(hdst + (ks - 4) * 32 + quad * 8);
#pragma unroll
    for (int nt = 0; nt < 4; nt++) {
      bf16x8 b = W1v[((colG * 4 + nt) * 8 + ks) * 64 + lane];
      acc[nt] = __builtin_amdgcn_mfma_f32_16x16x32_bf16(a, b, acc[nt], 0, 0, 0);
    }
  }
  // t1 epilogue -> Tbuf
#pragma unroll
  for (int nt = 0; nt < 4; nt++) {
    int col = colBase + nt * 16 + l16;
    float bb = bm1s[col], wc = w1cs[col];
#pragma unroll
    for (int reg = 0; reg < 4; reg++) {
      int row = rowBase + quad * 4 + reg;
      float v = acc[nt][reg] + bb + dists[row] * wc;
      Tbuf[tswz(row, col)] = (bf16)silu_f(v);
    }
  }
  __syncthreads();   // T complete (both col halves)

  // ---- layer 2: K = 128 -> messages ----
#pragma unroll
  for (int nt = 0; nt < 4; nt++) acc[nt] = (f32x4){0.f, 0.f, 0.f, 0.f};
#pragma unroll
  for (int ks = 0; ks < 4; ks++) {
    bf16x8 a = *(const bf16x8*)&Tbuf[tswz(rowBase + l16, ks * 32 + quad * 8)];
#pragma unroll
    for (int nt = 0; nt < 4; nt++) {
      bf16x8 b = W2v[((colG * 4 + nt) * 4 + ks) * 64 + lane];
      acc[nt] = __builtin_amdgcn_mfma_f32_16x16x32_bf16(a, b, acc[nt], 0, 0, 0);
    }
  }
  __syncthreads();   // all layer-2 reads of T done; safe to overwrite
#pragma unroll
  for (int nt = 0; nt < 4; nt++) {
    int col = colBase + nt * 16 + l16;
    float bb = bm2s[col];
#pragma unroll
    for (int reg = 0; reg < 4; reg++) {
      int row = rowBase + quad * 4 + reg;
      Tbuf[tswz(row, col)] = (bf16)silu_f(acc[nt][reg] + bb);
    }
  }
  __syncthreads();   // messages complete

  // ---- coord head: silu(messages @ Wc1 + bc1) @ Wc2 ----
#pragma unroll
  for (int nt = 0; nt < 4; nt++) acc[nt] = (f32x4){0.f, 0.f, 0.f, 0.f};
#pragma unroll
  for (int ks = 0; ks < 4; ks++) {
    bf16x8 a = *(const bf16x8*)&Tbuf[tswz(rowBase + l16, ks * 32 + quad * 8)];
#pragma unroll
    for (int nt = 0; nt < 4; nt++) {
      bf16x8 b = Wc1v[((colG * 4 + nt) * 4 + ks) * 64 + lane];
      acc[nt] = __builtin_amdgcn_mfma_f32_16x16x32_bf16(a, b, acc[nt], 0, 0, 0);
    }
  }

  // copy this wave's 16 rows x 64 cols of messages to global (16B chunks)
#pragma unroll
  for (int i = 0; i < 2; i++) {
    int item = i * 64 + lane;
    int row = rowBase + (item >> 3);
    int cg = colG * 8 + (item & 7);
    *(bf16x8*)&msgOut[(size_t)(blk * 32 + row) * H + cg * 8] =
        *(const bf16x8*)&Tbuf[tswz(row, cg * 8)];
  }

  float cwp[4] = {0.f, 0.f, 0.f, 0.f};
#pragma unroll
  for (int nt = 0; nt < 4; nt++) {
    int col = colBase + nt * 16 + l16;
    float bb = bc1s[col], w2 = wc2s[col];
#pragma unroll
    for (int reg = 0; reg < 4; reg++)
      cwp[reg] += silu_f(acc[nt][reg] + bb) * w2;
  }
#pragma unroll
  for (int reg = 0; reg < 4; reg++) {
    float s = cwp[reg];
    s += __shfl_xor(s, 1);
    s += __shfl_xor(s, 2);
    s += __shfl_xor(s, 4);
    s += __shfl_xor(s, 8);
    cwp[reg] = s;
  }
  if (l16 == 0) {
#pragma unroll
    for (int reg = 0; reg < 4; reg++)
      cwpart[colG][rowBase + quad * 4 + reg] = cwp[reg];
  }
  __syncthreads();   // both col-halves' partials in
  if (colG == 0 && l16 == 0) {
#pragma unroll
    for (int reg = 0; reg < 4; reg++) {
      int row = rowBase + quad * 4 + reg;
      size_t Rg = (size_t)blk * 32 + row;
      float cw = cwpart[0][row] + cwpart[1][row];
      float inv = 1.0f / (dists[row] + 1e-8f);
#pragma unroll
      for (int c = 0; c < 3; c++)
        updv[Rg * 3 + c] = cds[row * 3 + c] * inv * cw;
    }
  }
}

// ---------------- node kernel (2-phase: coalesced gather, N-split MFMA) ----
// Phase 1: thread = (row, 32B chunk). 8 threads fully cover each 256B msg
// row (coalesced); fp32 acc in regs -> bf16 agg tile in LDS. x_out fused.
// Phase 2: waves = 2 row-grp x 2 col-grp, acc[4] (16 AGPR) -> ~8 waves/SIMD.
__global__ __launch_bounds__(256, 6) void node_kernel(
    const float* __restrict__ h, const bf16* __restrict__ hb,
    const bf16* __restrict__ msg, const float* __restrict__ updv,
    const int* __restrict__ degI, const int* __restrict__ adj2,
    const bf16* __restrict__ Wn1p, const float* __restrict__ bn1,
    const bf16* __restrict__ Wn2p, const float* __restrict__ bn2,
    const float* __restrict__ x,
    float* __restrict__ hout, float* __restrict__ xout) {
  __shared__ __align__(16) bf16 Abuf[32 * 128];
  __shared__ __align__(16) bf16 Tbuf[32 * 128];

  const int tid = threadIdx.x, blk = blockIdx.x;

  // ---- phase 1: gather ----
  {
    const int row = tid >> 3, c8 = tid & 7;       // 32 rows x 8 chunks
    const int Rg = blk * 32 + row;                // batch*NA + atom
    const int atomA = Rg % NA, batA = Rg / NA;
    int deg = degI[atomA];
    if (deg > ADJ_CAP) deg = ADJ_CAP;
    const int* ap = adj2 + atomA * ADJ_CAP;
    float a16[16];
#pragma unroll
    for (int t = 0; t < 16; t++) a16[t] = 0.f;
    float sx = 0.f, sy = 0.f, sz = 0.f;
    int j = 0;
    for (; j + 2 <= deg; j += 2) {
      int ent0 = ap[j], ent1 = ap[j + 1];
      const bf16* m0 = msg + ((size_t)(ent0 >> 1) * 8 + batA) * H + c8 * 16;
      const bf16* m1 = msg + ((size_t)(ent1 >> 1) * 8 + batA) * H + c8 * 16;
      bf16x8 v0 = *(const bf16x8*)(m0);
      bf16x8 v1 = *(const bf16x8*)(m0 + 8);
      bf16x8 u0 = *(const bf16x8*)(m1);
      bf16x8 u1 = *(const bf16x8*)(m1 + 8);
      if (c8 == 0) {
        float sg0 = (ent0 & 1) ? 1.0f : -1.0f;
        float sg1 = (ent1 & 1) ? 1.0f : -1.0f;
        const float* uv0 = updv + ((size_t)(ent0 >> 1) * 8 + batA) * 3;
        const float* uv1 = updv + ((size_t)(ent1 >> 1) * 8 + batA) * 3;
        sx += sg0 * uv0[0] + sg1 * uv1[0];
        sy += sg0 * uv0[1] + sg1 * uv1[1];
        sz += sg0 * uv0[2] + sg1 * uv1[2];
      }
#pragma unroll
      for (int t = 0; t < 8; t++) {
        a16[t]     += (float)v0[t] + (float)u0[t];
        a16[8 + t] += (float)v1[t] + (float)u1[t];
      }
    }
    if (j < deg) {
      int ent0 = ap[j];
      const bf16* m0 = msg + ((size_t)(ent0 >> 1) * 8 + batA) * H + c8 * 16;
      bf16x8 v0 = *(const bf16x8*)(m0);
      bf16x8 v1 = *(const bf16x8*)(m0 + 8);
      if (c8 == 0) {
        float sg0 = (ent0 & 1) ? 1.0f : -1.0f;
        const float* uv0 = updv + ((size_t)(ent0 >> 1) * 8 + batA) * 3;
        sx += sg0 * uv0[0]; sy += sg0 * uv0[1]; sz += sg0 * uv0[2];
      }
#pragma unroll
      for (int t = 0; t < 8; t++) {
        a16[t]     += (float)v0[t];
        a16[8 + t] += (float)v1[t];
      }
    }
    if (c8 == 0) {   // x finalize
      float cnt = deg < 1 ? 1.0f : (float)deg;
      float inv = 1.0f / cnt;
      size_t o = (size_t)Rg * 3;
      xout[o + 0] = x[o + 0] + sx * inv;
      xout[o + 1] = x[o + 1] + sy * inv;
      xout[o + 2] = x[o + 2] + sz * inv;
    }
    bf16x8 w0, w1;
#pragma unroll
    for (int t = 0; t < 8; t++) { w0[t] = (bf16)a16[t]; w1[t] = (bf16)a16[8 + t]; }
    *(bf16x8*)&Abuf[tswz(row, c8 * 16)]     = w0;
    *(bf16x8*)&Abuf[tswz(row, c8 * 16 + 8)] = w1;
  }
  __syncthreads();   // agg tile ready

  // ---- phase 2: node MLP, N-split ----
  const int lane = tid & 63, wave = tid >> 6;
  const int quad = lane >> 4, l16 = lane & 15;
  const int rowG = (wave >> 1) * 16, colG = wave & 1, colBase = colG * 64;
  const int RgA = blk * 32 + rowG + l16;
  const bf16* hrow = hb + (size_t)RgA * H;
  const bf16x8* W1v = (const bf16x8*)Wn1p;
  const bf16x8* W2v = (const bf16x8*)Wn2p;

  f32x4 acc[4];
#pragma unroll
  for (int nt = 0; nt < 4; nt++) acc[nt] = (f32x4){0.f, 0.f, 0.f, 0.f};

  // layer-1 first half: h (bf16) register-direct from global
#pragma unroll
  for (int ks = 0; ks < 4; ks++) {
    bf16x8 a = *(const bf16x8*)(hrow + ks * 32 + quad * 8);
#pragma unroll
    for (int nt = 0; nt < 4; nt++) {
      bf16x8 b = W1v[((colG * 4 + nt) * 8 + ks) * 64 + lane];
      acc[nt] = __builtin_amdgcn_mfma_f32_16x16x32_bf16(a, b, acc[nt], 0, 0, 0);
    }
  }
  // layer-1 second half: aggregated from LDS
#pragma unroll
  for (int ks2 = 0; ks2 < 4; ks2++) {
    bf16x8 a = *(const bf16x8*)&Abuf[tswz(rowG + l16, ks2 * 32 + quad * 8)];
#pragma unroll
    for (int nt = 0; nt < 4; nt++) {
      bf16x8 b = W1v[((colG * 4 + nt) * 8 + 4 + ks2) * 64 + lane];
      acc[nt] = __builtin_amdgcn_mfma_f32_16x16x32_bf16(a, b, acc[nt], 0, 0, 0);
    }
  }
#pragma unroll
  for (int nt = 0; nt < 4; nt++) {
    int col = colBase + nt * 16 + l16;
    float bb = bn1[col];
#pragma unroll
    for (int reg = 0; reg < 4; reg++) {
      int row = rowG + quad * 4 + reg;
      Tbuf[tswz(row, col)] = (bf16)silu_f(acc[nt][reg] + bb);
    }
  }
  __syncthreads();   // T complete (both col halves)

#pragma unroll
  for (int nt = 0; nt < 4; nt++) acc[nt] = (f32x4){0.f, 0.f, 0.f, 0.f};
#pragma unroll
  for (int ks = 0; ks < 4; ks++) {
    bf16x8 a = *(const bf16x8*)&Tbuf[tswz(rowG + l16, ks * 32 + quad * 8)];
#pragma unroll
    for (int nt = 0; nt < 4; nt++) {
      bf16x8 b = W2v[((colG * 4 + nt) * 4 + ks) * 64 + lane];
      acc[nt] = __builtin_amdgcn_mfma_f32_16x16x32_bf16(a, b, acc[nt], 0, 0, 0);
    }
  }
#pragma unroll
  for (int nt = 0; nt < 4; nt++) {
    int col = colBase + nt * 16 + l16;
    float bb = bn2[col];
#pragma unroll
    for (int reg = 0; reg < 4; reg++) {
      size_t Ro = (size_t)blk * 32 + rowG + quad * 4 + reg;
      hout[Ro * H + col] = h[Ro * H + col] + acc[nt][reg] + bb;
    }
  }
}

extern "C" void kernel_launch(void* const* d_in, const int* in_sizes, int n_in,
                              void* d_out, int out_size, void* d_ws,
                              size_t ws_size, hipStream_t stream) {
  const float* h    = (const float*)d_in[0];
  const float* x    = (const float*)d_in[1];
  const int*  bonds = (const int*)d_in[2];
  const float* Wm1  = (const float*)d_in[3];
  const float* bm1  = (const float*)d_in[4];
  const float* Wm2  = (const float*)d_in[5];
  const float* bm2  = (const float*)d_in[6];
  const float* Wn1  = (const float*)d_in[7];
  const float* bn1  = (const float*)d_in[8];
  const float* Wn2  = (const float*)d_in[9];
  const float* bn2  = (const float*)d_in[10];
  const float* Wc1  = (const float*)d_in[11];
  const float* bc1  = (const float*)d_in[12];
  const float* Wc2  = (const float*)d_in[13];

  float* out  = (float*)d_out;
  float* hout = out;
  float* xout = out + (size_t)NBATCH * NA * H;

  char* ws = (char*)d_ws;
  // layout (bytes): NEED = 172,553,216 < 173,080,576 proven available.
  const size_t OFF_DEG  = 0;                        // NA int = 80,000
  const size_t OFF_W1   = 163840;                   // 65,536
  const size_t OFF_W2   = OFF_W1 + 65536;           // 32,768
  const size_t OFF_WN1  = OFF_W2 + 32768;           // 65,536
  const size_t OFF_WN2  = OFF_WN1 + 65536;          // 32,768
  const size_t OFF_WC1  = OFF_WN2 + 32768;          // 32,768 (ends 393,216)
  const size_t OFF_ADJ2 = 393216;                   // NA*32 int = 2,560,000
  const size_t OFF_UPDV = 2953216;                  // NB*8*3 f32 = 5,760,000
  const size_t OFF_HB   = 8713216;                  // 160000*128 bf16 = 40,960,000
  const size_t OFF_MSG  = 49673216;                 // NB*8*128 bf16 = 122,880,000

  int*   degI = (int*)(ws + OFF_DEG);
  bf16*  W1p  = (bf16*)(ws + OFF_W1);
  bf16*  W2p  = (bf16*)(ws + OFF_W2);
  bf16*  Wn1p = (bf16*)(ws + OFF_WN1);
  bf16*  Wn2p = (bf16*)(ws + OFF_WN2);
  bf16*  Wc1p = (bf16*)(ws + OFF_WC1);
  int*   adj2 = (int*)(ws + OFF_ADJ2);
  float* updv = (float*)(ws + OFF_UPDV);
  bf16*  hb   = (bf16*)(ws + OFF_HB);
  bf16*  msgB = (bf16*)(ws + OFF_MSG);

  (void)hipMemsetAsync(degI, 0, NA * sizeof(int), stream);

  cast_h<<<NBATCH * NA * H / 1024, 256, 0, stream>>>(h, hb);
  pack_w<<<128, 256, 0, stream>>>(Wm1, W1p, 256);
  pack_w<<<64, 256, 0, stream>>>(Wm2, W2p, 128);
  pack_w<<<128, 256, 0, stream>>>(Wn1, Wn1p, 256);
  pack_w<<<64, 256, 0, stream>>>(Wn2, Wn2p, 128);
  pack_w<<<64, 256, 0, stream>>>(Wc1, Wc1p, 128);

  build_adj2<<<(NB + 255) / 256, 256, 0, stream>>>(bonds, degI, adj2);

  msg_kernel<<<NB * NBATCH / 32, 256, 0, stream>>>(
      hb, x, bonds, W1p, bm1, W2p, bm2, Wm1 + 256 * H, Wc1p, bc1, Wc2,
      msgB, updv);
  node_kernel<<<NBATCH * NA / 32, 256, 0, stream>>>(
      h, hb, msgB, updv, degI, adj2, Wn1p, bn1, Wn2p, bn2, x,
      hout, xout);
}